// Round 14
// baseline (384.994 us; speedup 1.0000x reference)
//
#include <hip/hip_runtime.h>

// ---------------- problem constants ----------------
#define NFFT    2048
#define HOPSZ   512
#define BATCH   8
#define TFRAMES 2048
#define FBINS   1025
#define OUTLEN  1048064           // HOP*(T-1)
#define TOTALP  1050112           // NFFT + HOP*(T-1)
#define MROWS   16384             // BATCH*TFRAMES

__device__ __forceinline__ float bf2f(unsigned short h) {
    return __uint_as_float(((unsigned)h) << 16);
}

__device__ __forceinline__ float2 cmul(float2 a, float2 b) {
    return float2{a.x * b.x - a.y * b.y, a.x * b.y + a.y * b.x};
}
__device__ __forceinline__ float2 cadd(float2 a, float2 b) { return float2{a.x + b.x, a.y + b.y}; }
__device__ __forceinline__ float2 csub(float2 a, float2 b) { return float2{a.x - b.x, a.y - b.y}; }
__device__ __forceinline__ float2 cjmul(float2 a) { return float2{-a.y, a.x}; }   // i*a

// inverse DFT-4: y[r] = sum_j x[j] * i^{r j}
#define IDFT4(y0, y1, y2, y3, x0, x1, x2, x3) do {                         \
    float2 t0 = cadd(x0, x2), t1 = csub(x0, x2);                           \
    float2 t2 = cadd(x1, x3), t3 = cjmul(csub(x1, x3));                    \
    y0 = cadd(t0, t2); y2 = csub(t0, t2);                                  \
    y1 = cadd(t1, t3); y3 = csub(t1, t3); } while (0)

// inverse DFT-16 (radix-4 x radix-4, four-step)
__device__ __forceinline__ void idft16(float2* y, const float2* x) {
    const float c1 = 0.92387953251128674f, s1 = 0.38268343236508977f;   // cos/sin pi/8
    const float r2 = 0.70710678118654752f;
    float2 A[16];
    #pragma unroll
    for (int jb = 0; jb < 4; ++jb)
        IDFT4(A[jb * 4 + 0], A[jb * 4 + 1], A[jb * 4 + 2], A[jb * 4 + 3],
              x[jb], x[4 + jb], x[8 + jb], x[12 + jb]);
    A[4 + 1]  = cmul(A[4 + 1],  float2{c1, s1});
    A[4 + 2]  = cmul(A[4 + 2],  float2{r2, r2});
    A[4 + 3]  = cmul(A[4 + 3],  float2{s1, c1});
    A[8 + 1]  = cmul(A[8 + 1],  float2{r2, r2});
    A[8 + 2]  = cjmul(A[8 + 2]);
    A[8 + 3]  = cmul(A[8 + 3],  float2{-r2, r2});
    A[12 + 1] = cmul(A[12 + 1], float2{s1, c1});
    A[12 + 2] = cmul(A[12 + 2], float2{-r2, r2});
    A[12 + 3] = cmul(A[12 + 3], float2{-c1, -s1});
    #pragma unroll
    for (int ra = 0; ra < 4; ++ra)
        IDFT4(y[ra], y[ra + 4], y[ra + 8], y[ra + 12],
              A[ra], A[4 + ra], A[8 + ra], A[12 + ra]);
}

// tree-factored twiddle apply: A[n] *= w1^n, n = 1..15 (depth 4, wide ILP)
__device__ __forceinline__ void twiddle16(float2* __restrict__ A, float2 w1) {
    float2 w2  = cmul(w1, w1);
    float2 w3  = cmul(w1, w2);
    float2 w4  = cmul(w2, w2);
    float2 w5  = cmul(w1, w4);
    float2 w6  = cmul(w2, w4);
    float2 w7  = cmul(w3, w4);
    float2 w8  = cmul(w4, w4);
    float2 w9  = cmul(w1, w8);
    float2 w10 = cmul(w2, w8);
    float2 w11 = cmul(w3, w8);
    float2 w12 = cmul(w4, w8);
    float2 w13 = cmul(w5, w8);
    float2 w14 = cmul(w6, w8);
    float2 w15 = cmul(w7, w8);
    A[1]  = cmul(A[1],  w1);   A[2]  = cmul(A[2],  w2);
    A[3]  = cmul(A[3],  w3);   A[4]  = cmul(A[4],  w4);
    A[5]  = cmul(A[5],  w5);   A[6]  = cmul(A[6],  w6);
    A[7]  = cmul(A[7],  w7);   A[8]  = cmul(A[8],  w8);
    A[9]  = cmul(A[9],  w9);   A[10] = cmul(A[10], w10);
    A[11] = cmul(A[11], w11);  A[12] = cmul(A[12], w12);
    A[13] = cmul(A[13], w13);  A[14] = cmul(A[14], w14);
    A[15] = cmul(A[15], w15);
}

// e^{i pi k1/16} constants
__constant__ float WKC[16] = { 1.0f, 0.98078528040323044f, 0.92387953251128674f, 0.83146961230254524f,
                               0.70710678118654752f, 0.55557023301960222f, 0.38268343236508977f, 0.19509032201612827f,
                               0.0f, -0.19509032201612827f, -0.38268343236508977f, -0.55557023301960222f,
                               -0.70710678118654752f, -0.83146961230254524f, -0.92387953251128674f, -0.98078528040323044f };
__constant__ float WKS[16] = { 0.0f, 0.19509032201612827f, 0.38268343236508977f, 0.55557023301960222f,
                               0.70710678118654752f, 0.83146961230254524f, 0.92387953251128674f, 0.98078528040323044f,
                               1.0f, 0.98078528040323044f, 0.92387953251128674f, 0.83146961230254524f,
                               0.70710678118654752f, 0.55557023301960222f, 0.38268343236508977f, 0.19509032201612827f };

// ---------------- window table: wt[n] = (win[2n], win[2n+1]) * (1/2048) -----
__global__ void build_tabs(float2* __restrict__ wt) {
    int n = blockIdx.x * 256 + threadIdx.x;
    const float s = 1.0f / 2048.0f;
    if (n < 1024)
        wt[n] = float2{(0.5f - 0.5f * cospif((float)(2 * n)     * (1.0f / 1024.0f))) * s,
                       (0.5f - 0.5f * cospif((float)(2 * n + 1) * (1.0f / 1024.0f))) * s};
}

// ---------------- per-frame irfft: wave-per-frame four-step register FFT ----
// 1024 = 16 x 64 Bailey four-step (verified r10-r13). LDS transpose done in
// TWO 4KB passes (by n1-halves) to halve per-wave LDS: pass1 writes A[0..7],
// lanes n1r<8 read; pass2 overwrites with A[8..15], lanes n1r>=8 read.
// 2 waves / 128-thread block, 8KB LDS/block. Compiler manages same-wave
// LDS ordering (wave-private buffer, no barriers).
__global__ __launch_bounds__(128, 8) void fft_frames(
    const float* __restrict__ re, const float* __restrict__ im,
    const float2* __restrict__ wt,
    unsigned short* __restrict__ Y)          // [BATCH][4][TOTALP] bf16
{
    __shared__ float2 tb[2][512];            // 4KB per wave

    const int tid   = threadIdx.x;
    const int lane  = tid & 63;
    const int wv    = tid >> 6;
    const int frame = blockIdx.x * 2 + wv;
    const int b     = frame >> 11;
    const int t     = frame & (TFRAMES - 1);
    const float* rr = re + (size_t)frame * FBINS;
    const float* ii = im + (size_t)frame * FBINS;
    float2* tbw     = tb[wv];

    // per-lane twiddle bases (only transcendentals in the kernel)
    const float2 packb = float2{cospif((float)lane * (1.0f / 1024.0f)),
                                sinpif((float)lane * (1.0f / 1024.0f))};  // e^{i pi l/1024}
    const float2 base2 = cmul(packb, packb);                              // e^{2pi i l/1024}

    // ---- pack: zz[k1] = Z[64*k1 + lane] ----
    float2 zz[16];
    #pragma unroll
    for (int k1 = 0; k1 < 16; ++k1) {
        const int m = 64 * k1 + lane;
        float Xr = rr[m],        Xi = ii[m];
        float Cr = rr[1024 - m], Ni = ii[1024 - m];
        float2 W = cmul(packb, float2{WKC[k1], WKS[k1]});   // e^{i pi m/1024}
        float Er = Xr + Cr, Ei = Xi - Ni;
        float Or = Xr - Cr, Oi = Xi + Ni;
        float2 z = float2{Er - (W.x * Oi + W.y * Or), Ei + (W.x * Or - W.y * Oi)};
        if (k1 == 0 && lane == 0)                           // m == 0: im parts drop
            z = float2{Xr + Cr, Xr - Cr};
        zz[k1] = z;
    }

    // ---- step 1: A = idft16 over k1 ----
    float2 A[16];
    idft16(A, zz);

    // ---- step 2: A[n1] *= W1024^{n1*lane} (tree-factored) ----
    twiddle16(A, base2);

    const int q   = lane >> 4;
    const int n1r = lane & 15;
    float2 D[16];

    // ---- transpose pass 1: write A[0..7] (4KB), lanes n1r<8 read ----
    {
        float4* rowp = (float4*)&tbw[lane * 8];
        #pragma unroll
        for (int j = 0; j < 4; ++j) {
            float2 e = A[2 * j], o = A[2 * j + 1];
            rowp[(j + lane) & 3] = float4{e.x, e.y, o.x, o.y};
        }
    }
    if (n1r < 8) {
        #pragma unroll
        for (int c1 = 0; c1 < 16; ++c1) {
            const int row = 4 * c1 + q;
            D[c1] = tbw[row * 8 + (((n1r >> 1) + row) & 3) * 2 + (n1r & 1)];
        }
    }
    // ---- transpose pass 2: overwrite with A[8..15], lanes n1r>=8 read ----
    {
        float4* rowp = (float4*)&tbw[lane * 8];
        #pragma unroll
        for (int j = 0; j < 4; ++j) {
            float2 e = A[8 + 2 * j], o = A[9 + 2 * j];
            rowp[(j + lane) & 3] = float4{e.x, e.y, o.x, o.y};
        }
    }
    if (n1r >= 8) {
        const int n1h = n1r - 8;
        #pragma unroll
        for (int c1 = 0; c1 < 16; ++c1) {
            const int row = 4 * c1 + q;
            D[c1] = tbw[row * 8 + (((n1h >> 1) + row) & 3) * 2 + (n1h & 1)];
        }
    }

    // ---- step 3a: E = idft16 over c1 ----
    float2 E[16];
    idft16(E, D);

    // ---- step 3b: E[v1] *= W64^{v1*q} (tree-factored; base selected by q) ----
    {
        float2 bq = (q == 0) ? float2{1.0f, 0.0f}
                  : (q == 1) ? float2{0.99518472667219693f, 0.09801714032956060f}
                  : (q == 2) ? float2{0.98078528040323044f, 0.19509032201612827f}
                             : float2{0.95694033573220886f, 0.29028467725446237f};
        twiddle16(E, bq);
    }

    // ---- step 3c: cross-lane idft4 over q + window + bf16 plane store ----
    unsigned short* Yb = Y + ((size_t)(b * 4 + (t & 3))) * TOTALP + t * HOPSZ;
    const int v2 = ((q & 1) << 1) | (q >> 1);          // bitrev2(q)
    const int nbase = n1r + (v2 << 8);
    #pragma unroll
    for (int v1 = 0; v1 < 16; ++v1) {
        float2 mine = E[v1];
        float2 oth  = float2{__shfl_xor(mine.x, 32), __shfl_xor(mine.y, 32)};
        float2 G    = (lane < 32) ? cadd(mine, oth) : csub(oth, mine);
        float2 o2   = float2{__shfl_xor(G.x, 16), __shfl_xor(G.y, 16)};
        float2 res;
        if (q == 0)      res = cadd(G, o2);                         // -> v2=0
        else if (q == 1) res = csub(o2, G);                         // -> v2=2
        else if (q == 2) res = float2{G.x - o2.y, G.y + o2.x};      // -> v2=1
        else             res = float2{o2.x + G.y, o2.y - G.x};      // -> v2=3
        const int n = nbase + (v1 << 4);
        const float2 wp = wt[n];                // window * (1/2048)
        const float lo = res.x * wp.x, hi = res.y * wp.y;
        unsigned pack;
        asm("v_cvt_pk_bf16_f32 %0, %1, %2" : "=v"(pack) : "v"(lo), "v"(hi));
        *(unsigned*)(Yb + 2 * n) = pack;
    }
}

// ---------------- final pass: gather 4 planes, divide by window-sumsquare ---
__global__ __launch_bounds__(256) void final_pass(
    const unsigned short* __restrict__ Y,    // [BATCH][4][TOTALP]
    const float2*         __restrict__ wt,   // window pairs * s
    float*                __restrict__ out)  // [BATCH][OUTLEN]
{
    const int tx = blockIdx.x * 256 + threadIdx.x;
    if (tx >= OUTLEN / 8) return;
    const int b  = blockIdx.y;
    const int n0 = tx * 8;
    const int p0 = n0 + 1024;
    int tmin = (p0 - 1536) >> 9;  if (tmin < 0) tmin = 0;
    int tmax = p0 >> 9;           if (tmax > TFRAMES - 1) tmax = TFRAMES - 1;

    float acc[8], ws[8];
    #pragma unroll
    for (int j = 0; j < 8; ++j) { acc[j] = 0.0f; ws[j] = 0.0f; }

    for (int t = tmin; t <= tmax; ++t) {
        const int a0 = p0 - t * HOPSZ;        // 8-run fully inside [0,2048)
        const uint4 pv = *(const uint4*)(Y + ((size_t)(b * 4 + (t & 3))) * TOTALP + p0);
        const unsigned pw[4] = {pv.x, pv.y, pv.z, pv.w};
        #pragma unroll
        for (int j = 0; j < 4; ++j) {
            acc[2 * j]     += bf2f((unsigned short)(pw[j] & 0xffffu));
            acc[2 * j + 1] += bf2f((unsigned short)(pw[j] >> 16));
        }
        #pragma unroll
        for (int j = 0; j < 4; ++j) {
            float2 w = wt[(a0 >> 1) + j];     // (win[a0+2j], win[a0+2j+1]) * s
            ws[2 * j]     += w.x * w.x;
            ws[2 * j + 1] += w.y * w.y;
        }
    }
    const float S2 = (1.0f / 2048.0f) * (1.0f / 2048.0f);
    float r[8];
    #pragma unroll
    for (int j = 0; j < 8; ++j) r[j] = acc[j] * S2 / fmaxf(ws[j], 2.4e-15f);
    float4* o = (float4*)(out + (size_t)b * OUTLEN + n0);
    o[0] = float4{r[0], r[1], r[2], r[3]};
    o[1] = float4{r[4], r[5], r[6], r[7]};
}

// ---------------- launch -----------------------------------------------------
extern "C" void kernel_launch(void* const* d_in, const int* in_sizes, int n_in,
                              void* d_out, int out_size, void* d_ws, size_t ws_size,
                              hipStream_t stream) {
    const float* re = (const float*)d_in[0];
    const float* im = (const float*)d_in[1];
    float* out = (float*)d_out;

    char* ws = (char*)d_ws;
    unsigned short* Y  = (unsigned short*)(ws);            // 8*4*1050112*2 = 67,207,168 B
    float2*         wt = (float2*)       (ws + 67207168);  // 1024*8 = 8,192 B

    build_tabs<<<dim3(4),          256, 0, stream>>>(wt);
    fft_frames<<<dim3(MROWS / 2), 128, 0, stream>>>(re, im, wt, Y);
    final_pass<<<dim3(512, BATCH), 256, 0, stream>>>(Y, wt, out);
}

// Round 15
// 118.969 us; speedup vs baseline: 3.2361x; 3.2361x over previous
//
#include <hip/hip_runtime.h>

// ---------------- problem constants ----------------
#define NFFT    2048
#define HOPSZ   512
#define BATCH   8
#define TFRAMES 2048
#define FBINS   1025
#define OUTLEN  1048064           // HOP*(T-1)
#define TOTALP  1050112           // NFFT + HOP*(T-1)
#define MROWS   16384             // BATCH*TFRAMES

__device__ __forceinline__ float bf2f(unsigned short h) {
    return __uint_as_float(((unsigned)h) << 16);
}

__device__ __forceinline__ float2 cmul(float2 a, float2 b) {
    return float2{a.x * b.x - a.y * b.y, a.x * b.y + a.y * b.x};
}
__device__ __forceinline__ float2 cadd(float2 a, float2 b) { return float2{a.x + b.x, a.y + b.y}; }
__device__ __forceinline__ float2 csub(float2 a, float2 b) { return float2{a.x - b.x, a.y - b.y}; }
__device__ __forceinline__ float2 cjmul(float2 a) { return float2{-a.y, a.x}; }   // i*a

// inverse DFT-4: y[r] = sum_j x[j] * i^{r j}
#define IDFT4(y0, y1, y2, y3, x0, x1, x2, x3) do {                         \
    float2 t0 = cadd(x0, x2), t1 = csub(x0, x2);                           \
    float2 t2 = cadd(x1, x3), t3 = cjmul(csub(x1, x3));                    \
    y0 = cadd(t0, t2); y2 = csub(t0, t2);                                  \
    y1 = cadd(t1, t3); y3 = csub(t1, t3); } while (0)

// inverse DFT-16 (radix-4 x radix-4, four-step)
__device__ __forceinline__ void idft16(float2* y, const float2* x) {
    const float c1 = 0.92387953251128674f, s1 = 0.38268343236508977f;   // cos/sin pi/8
    const float r2 = 0.70710678118654752f;
    float2 A[16];
    #pragma unroll
    for (int jb = 0; jb < 4; ++jb)
        IDFT4(A[jb * 4 + 0], A[jb * 4 + 1], A[jb * 4 + 2], A[jb * 4 + 3],
              x[jb], x[4 + jb], x[8 + jb], x[12 + jb]);
    A[4 + 1]  = cmul(A[4 + 1],  float2{c1, s1});
    A[4 + 2]  = cmul(A[4 + 2],  float2{r2, r2});
    A[4 + 3]  = cmul(A[4 + 3],  float2{s1, c1});
    A[8 + 1]  = cmul(A[8 + 1],  float2{r2, r2});
    A[8 + 2]  = cjmul(A[8 + 2]);
    A[8 + 3]  = cmul(A[8 + 3],  float2{-r2, r2});
    A[12 + 1] = cmul(A[12 + 1], float2{s1, c1});
    A[12 + 2] = cmul(A[12 + 2], float2{-r2, r2});
    A[12 + 3] = cmul(A[12 + 3], float2{-c1, -s1});
    #pragma unroll
    for (int ra = 0; ra < 4; ++ra)
        IDFT4(y[ra], y[ra + 4], y[ra + 8], y[ra + 12],
              A[ra], A[4 + ra], A[8 + ra], A[12 + ra]);
}

// tree-factored twiddle apply: A[n] *= w1^n, n = 1..15 (depth 4, wide ILP)
__device__ __forceinline__ void twiddle16(float2* __restrict__ A, float2 w1) {
    float2 w2  = cmul(w1, w1);
    float2 w3  = cmul(w1, w2);
    float2 w4  = cmul(w2, w2);
    float2 w5  = cmul(w1, w4);
    float2 w6  = cmul(w2, w4);
    float2 w7  = cmul(w3, w4);
    float2 w8  = cmul(w4, w4);
    float2 w9  = cmul(w1, w8);
    float2 w10 = cmul(w2, w8);
    float2 w11 = cmul(w3, w8);
    float2 w12 = cmul(w4, w8);
    float2 w13 = cmul(w5, w8);
    float2 w14 = cmul(w6, w8);
    float2 w15 = cmul(w7, w8);
    A[1]  = cmul(A[1],  w1);   A[2]  = cmul(A[2],  w2);
    A[3]  = cmul(A[3],  w3);   A[4]  = cmul(A[4],  w4);
    A[5]  = cmul(A[5],  w5);   A[6]  = cmul(A[6],  w6);
    A[7]  = cmul(A[7],  w7);   A[8]  = cmul(A[8],  w8);
    A[9]  = cmul(A[9],  w9);   A[10] = cmul(A[10], w10);
    A[11] = cmul(A[11], w11);  A[12] = cmul(A[12], w12);
    A[13] = cmul(A[13], w13);  A[14] = cmul(A[14], w14);
    A[15] = cmul(A[15], w15);
}

// e^{i pi k1/16} constants
__constant__ float WKC[16] = { 1.0f, 0.98078528040323044f, 0.92387953251128674f, 0.83146961230254524f,
                               0.70710678118654752f, 0.55557023301960222f, 0.38268343236508977f, 0.19509032201612827f,
                               0.0f, -0.19509032201612827f, -0.38268343236508977f, -0.55557023301960222f,
                               -0.70710678118654752f, -0.83146961230254524f, -0.92387953251128674f, -0.98078528040323044f };
__constant__ float WKS[16] = { 0.0f, 0.19509032201612827f, 0.38268343236508977f, 0.55557023301960222f,
                               0.70710678118654752f, 0.83146961230254524f, 0.92387953251128674f, 0.98078528040323044f,
                               1.0f, 0.98078528040323044f, 0.92387953251128674f, 0.83146961230254524f,
                               0.70710678118654752f, 0.55557023301960222f, 0.38268343236508977f, 0.19509032201612827f };

// ---------------- window table: wt[n] = (win[2n], win[2n+1]) * (1/2048) -----
__global__ void build_tabs(float2* __restrict__ wt) {
    int n = blockIdx.x * 256 + threadIdx.x;
    const float s = 1.0f / 2048.0f;
    if (n < 1024)
        wt[n] = float2{(0.5f - 0.5f * cospif((float)(2 * n)     * (1.0f / 1024.0f))) * s,
                       (0.5f - 0.5f * cospif((float)(2 * n + 1) * (1.0f / 1024.0f))) * s};
}

// pack + step1 + step2: produce twiddled A[16] for one frame
__device__ __forceinline__ void stage12(const float* __restrict__ rr,
                                        const float* __restrict__ ii,
                                        int lane, float2 packb, float2 base2,
                                        float2* __restrict__ A)
{
    float2 zz[16];
    #pragma unroll
    for (int k1 = 0; k1 < 16; ++k1) {
        const int m = 64 * k1 + lane;
        float Xr = rr[m],        Xi = ii[m];
        float Cr = rr[1024 - m], Ni = ii[1024 - m];
        float2 W = cmul(packb, float2{WKC[k1], WKS[k1]});   // e^{i pi m/1024}
        float Er = Xr + Cr, Ei = Xi - Ni;
        float Or = Xr - Cr, Oi = Xi + Ni;
        float2 z = float2{Er - (W.x * Oi + W.y * Or), Ei + (W.x * Or - W.y * Oi)};
        if (k1 == 0 && lane == 0)                           // m == 0: im parts drop
            z = float2{Xr + Cr, Xr - Cr};
        zz[k1] = z;
    }
    idft16(A, zz);
    twiddle16(A, base2);
}

// step3: transpose-read from tb, dft16, W64 twiddle -> E[16]
__device__ __forceinline__ void stage3(const float2* __restrict__ tbw,
                                       int q, int n1r, float2* __restrict__ E)
{
    float2 D[16];
    #pragma unroll
    for (int c1 = 0; c1 < 16; ++c1) {
        const int row = 4 * c1 + q;
        D[c1] = tbw[row * 16 + (((n1r >> 1) + row) & 7) * 2 + (n1r & 1)];
    }
    idft16(E, D);
    float2 bq = (q == 0) ? float2{1.0f, 0.0f}
              : (q == 1) ? float2{0.99518472667219693f, 0.09801714032956060f}
              : (q == 2) ? float2{0.98078528040323044f, 0.19509032201612827f}
                         : float2{0.95694033573220886f, 0.29028467725446237f};
    twiddle16(E, bq);
}

// transpose write A -> tb (chunk-rotated)
__device__ __forceinline__ void twrite(float2* __restrict__ tbw, int lane,
                                       const float2* __restrict__ A)
{
    float4* rowp = (float4*)&tbw[lane * 16];
    #pragma unroll
    for (int j = 0; j < 8; ++j) {
        float2 e = A[2 * j], o = A[2 * j + 1];
        rowp[(j + lane) & 7] = float4{e.x, e.y, o.x, o.y};
    }
}

// cross-lane idft4 over q + window + bf16 plane store
__device__ __forceinline__ void tailstore(const float2* __restrict__ E,
                                          int lane, int q, int n1r,
                                          const float2* __restrict__ wt,
                                          unsigned short* __restrict__ Yb)
{
    const int v2 = ((q & 1) << 1) | (q >> 1);          // bitrev2(q)
    const int nbase = n1r + (v2 << 8);
    #pragma unroll
    for (int v1 = 0; v1 < 16; ++v1) {
        float2 mine = E[v1];
        float2 oth  = float2{__shfl_xor(mine.x, 32), __shfl_xor(mine.y, 32)};
        float2 G    = (lane < 32) ? cadd(mine, oth) : csub(oth, mine);
        float2 o2   = float2{__shfl_xor(G.x, 16), __shfl_xor(G.y, 16)};
        float2 res;
        if (q == 0)      res = cadd(G, o2);                         // -> v2=0
        else if (q == 1) res = csub(o2, G);                         // -> v2=2
        else if (q == 2) res = float2{G.x - o2.y, G.y + o2.x};      // -> v2=1
        else             res = float2{o2.x + G.y, o2.y - G.x};      // -> v2=3
        const int n = nbase + (v1 << 4);
        const float2 wp = wt[n];                // window * (1/2048)
        const float lo = res.x * wp.x, hi = res.y * wp.y;
        unsigned pack;
        asm("v_cvt_pk_bf16_f32 %0, %1, %2" : "=v"(pack) : "v"(lo), "v"(hi));
        *(unsigned*)(Yb + 2 * n) = pack;
    }
}

// ---------------- per-frame irfft: 2 frames per wave (ILP-2, uncapped regs) -
// 1024 = 16 x 64 Bailey four-step (verified r10-r13). One wave processes two
// frames with interleaved dataflows sharing one 8KB transpose buffer
// sequentially. NO register cap (r12's spill cause was the (128,4) bound);
// allocator free up to 256 VGPR -> 2-3 waves/SIMD x 2 frames each.
__global__ __launch_bounds__(128) void fft_frames(
    const float* __restrict__ re, const float* __restrict__ im,
    const float2* __restrict__ wt,
    unsigned short* __restrict__ Y)          // [BATCH][4][TOTALP] bf16
{
    __shared__ float2 tb[2][1024];           // 8KB per wave

    const int tid   = threadIdx.x;
    const int lane  = tid & 63;
    const int wv    = tid >> 6;
    const int fA    = blockIdx.x * 4 + wv * 2;    // frames fA, fA+1
    const int fB    = fA + 1;
    float2* tbw     = tb[wv];

    // per-lane twiddle bases (only transcendentals in the kernel)
    const float2 packb = float2{cospif((float)lane * (1.0f / 1024.0f)),
                                sinpif((float)lane * (1.0f / 1024.0f))};  // e^{i pi l/1024}
    const float2 base2 = cmul(packb, packb);                              // e^{2pi i l/1024}

    const int q   = lane >> 4;
    const int n1r = lane & 15;

    const float* rrA = re + (size_t)fA * FBINS;
    const float* iiA = im + (size_t)fA * FBINS;
    const float* rrB = re + (size_t)fB * FBINS;
    const float* iiB = im + (size_t)fB * FBINS;

    // ---- frame A: pack + dft16 + twiddle; write transpose ----
    float2 AA[16];
    stage12(rrA, iiA, lane, packb, base2, AA);
    twrite(tbw, lane, AA);

    // ---- frame B: pack + dft16 + twiddle (covers A's LDS latency) ----
    float2 AB[16];
    stage12(rrB, iiB, lane, packb, base2, AB);

    // ---- frame A: transpose read + dft16 + W64 ----
    float2 EA[16];
    stage3(tbw, q, n1r, EA);

    // ---- frame B: write transpose (after A's reads; same-wave ordered) ----
    twrite(tbw, lane, AB);

    // ---- frame A: tail + store ----
    {
        const int b = fA >> 11, t = fA & (TFRAMES - 1);
        unsigned short* Yb = Y + ((size_t)(b * 4 + (t & 3))) * TOTALP + t * HOPSZ;
        tailstore(EA, lane, q, n1r, wt, Yb);
    }

    // ---- frame B: transpose read + dft16 + W64; tail + store ----
    float2 EB[16];
    stage3(tbw, q, n1r, EB);
    {
        const int b = fB >> 11, t = fB & (TFRAMES - 1);
        unsigned short* Yb = Y + ((size_t)(b * 4 + (t & 3))) * TOTALP + t * HOPSZ;
        tailstore(EB, lane, q, n1r, wt, Yb);
    }
}

// ---------------- final pass: gather 4 planes, divide by window-sumsquare ---
__global__ __launch_bounds__(256) void final_pass(
    const unsigned short* __restrict__ Y,    // [BATCH][4][TOTALP]
    const float2*         __restrict__ wt,   // window pairs * s
    float*                __restrict__ out)  // [BATCH][OUTLEN]
{
    const int tx = blockIdx.x * 256 + threadIdx.x;
    if (tx >= OUTLEN / 8) return;
    const int b  = blockIdx.y;
    const int n0 = tx * 8;
    const int p0 = n0 + 1024;
    int tmin = (p0 - 1536) >> 9;  if (tmin < 0) tmin = 0;
    int tmax = p0 >> 9;           if (tmax > TFRAMES - 1) tmax = TFRAMES - 1;

    float acc[8], ws[8];
    #pragma unroll
    for (int j = 0; j < 8; ++j) { acc[j] = 0.0f; ws[j] = 0.0f; }

    for (int t = tmin; t <= tmax; ++t) {
        const int a0 = p0 - t * HOPSZ;        // 8-run fully inside [0,2048)
        const uint4 pv = *(const uint4*)(Y + ((size_t)(b * 4 + (t & 3))) * TOTALP + p0);
        const unsigned pw[4] = {pv.x, pv.y, pv.z, pv.w};
        #pragma unroll
        for (int j = 0; j < 4; ++j) {
            acc[2 * j]     += bf2f((unsigned short)(pw[j] & 0xffffu));
            acc[2 * j + 1] += bf2f((unsigned short)(pw[j] >> 16));
        }
        #pragma unroll
        for (int j = 0; j < 4; ++j) {
            float2 w = wt[(a0 >> 1) + j];     // (win[a0+2j], win[a0+2j+1]) * s
            ws[2 * j]     += w.x * w.x;
            ws[2 * j + 1] += w.y * w.y;
        }
    }
    const float S2 = (1.0f / 2048.0f) * (1.0f / 2048.0f);
    float r[8];
    #pragma unroll
    for (int j = 0; j < 8; ++j) r[j] = acc[j] * S2 / fmaxf(ws[j], 2.4e-15f);
    float4* o = (float4*)(out + (size_t)b * OUTLEN + n0);
    o[0] = float4{r[0], r[1], r[2], r[3]};
    o[1] = float4{r[4], r[5], r[6], r[7]};
}

// ---------------- launch -----------------------------------------------------
extern "C" void kernel_launch(void* const* d_in, const int* in_sizes, int n_in,
                              void* d_out, int out_size, void* d_ws, size_t ws_size,
                              hipStream_t stream) {
    const float* re = (const float*)d_in[0];
    const float* im = (const float*)d_in[1];
    float* out = (float*)d_out;

    char* ws = (char*)d_ws;
    unsigned short* Y  = (unsigned short*)(ws);            // 8*4*1050112*2 = 67,207,168 B
    float2*         wt = (float2*)       (ws + 67207168);  // 1024*8 = 8,192 B

    build_tabs<<<dim3(4),          256, 0, stream>>>(wt);
    fft_frames<<<dim3(MROWS / 4),  128, 0, stream>>>(re, im, wt, Y);
    final_pass<<<dim3(512, BATCH), 256, 0, stream>>>(Y, wt, out);
}

// Round 17
// 82.367 us; speedup vs baseline: 4.6741x; 1.4444x over previous
//
#include <hip/hip_runtime.h>

// ---------------- problem constants ----------------
#define NFFT    2048
#define HOPSZ   512
#define BATCH   8
#define TFRAMES 2048
#define FBINS   1025
#define OUTLEN  1048064           // HOP*(T-1)
#define TOTALP  1050112           // NFFT + HOP*(T-1)
#define MROWS   16384             // BATCH*TFRAMES

// tabs layout (f2 units):
//   [0..1023]    WT[n]  = (win[2n], win[2n+1]) * (1/2048)
//   [1024..2047] T2[n1*64+l] = e^{+2pi i n1 l/1024}   (step-2 twiddles)
//   [2048..2111] T64[q*16+v1] = e^{+2pi i q v1/64}    (step-3b twiddles)
//   [2112..3135] TP[m] = e^{+i pi m/1024}             (irfft pack twiddles)

typedef float f2 __attribute__((ext_vector_type(2)));

__device__ __forceinline__ float bf2f(unsigned short h) {
    return __uint_as_float(((unsigned)h) << 16);
}

// complex ops on packed f32 pairs -> v_pk_{add,mul,fma}_f32
__device__ __forceinline__ f2 cmul(f2 a, f2 b) {
    f2 r = a * f2{b.x, b.x};
    return __builtin_shufflevector(a, a, 1, 0) * f2{-b.y, b.y} + r;
}
__device__ __forceinline__ f2 cjmul(f2 a) {        // i*a
    return __builtin_shufflevector(a, a, 1, 0) * f2{-1.0f, 1.0f};
}

// inverse DFT-4: y[r] = sum_j x[j] * i^{r j}
#define IDFT4(y0, y1, y2, y3, x0, x1, x2, x3) do {                         \
    f2 t0 = x0 + x2, t1 = x0 - x2;                                         \
    f2 t2 = x1 + x3, jd = cjmul(x1 - x3);                                  \
    y0 = t0 + t2; y2 = t0 - t2;                                            \
    y1 = t1 + jd; y3 = t1 - jd; } while (0)

// inverse DFT-16 (radix-4 x radix-4, four-step)
__device__ __forceinline__ void idft16(f2* y, const f2* x) {
    const float c1 = 0.92387953251128674f, s1 = 0.38268343236508977f;   // cos/sin pi/8
    const float r2 = 0.70710678118654752f;
    f2 A[16];
    #pragma unroll
    for (int jb = 0; jb < 4; ++jb)
        IDFT4(A[jb * 4 + 0], A[jb * 4 + 1], A[jb * 4 + 2], A[jb * 4 + 3],
              x[jb], x[4 + jb], x[8 + jb], x[12 + jb]);
    A[4 + 1]  = cmul(A[4 + 1],  f2{c1, s1});
    A[4 + 2]  = cmul(A[4 + 2],  f2{r2, r2});
    A[4 + 3]  = cmul(A[4 + 3],  f2{s1, c1});
    A[8 + 1]  = cmul(A[8 + 1],  f2{r2, r2});
    A[8 + 2]  = cjmul(A[8 + 2]);
    A[8 + 3]  = cmul(A[8 + 3],  f2{-r2, r2});
    A[12 + 1] = cmul(A[12 + 1], f2{s1, c1});
    A[12 + 2] = cmul(A[12 + 2], f2{-r2, r2});
    A[12 + 3] = cmul(A[12 + 3], f2{-c1, -s1});
    #pragma unroll
    for (int ra = 0; ra < 4; ++ra)
        IDFT4(y[ra], y[ra + 4], y[ra + 8], y[ra + 12],
              A[ra], A[4 + ra], A[8 + ra], A[12 + ra]);
}

// ---------------- twiddle / window tables -----------------------------------
__global__ void build_tabs(f2* __restrict__ tabs) {
    int i = blockIdx.x * 256 + threadIdx.x;
    const float s = 1.0f / 2048.0f;
    if (i < 1024) {
        tabs[i] = f2{(0.5f - 0.5f * cospif((float)(2 * i)     * (1.0f / 1024.0f))) * s,
                     (0.5f - 0.5f * cospif((float)(2 * i + 1) * (1.0f / 1024.0f))) * s};
    } else if (i < 2048) {
        int j = i - 1024, n1 = j >> 6, l = j & 63;
        float ang = (float)(n1 * l) * (1.0f / 512.0f);
        tabs[i] = f2{cospif(ang), sinpif(ang)};
    } else if (i < 2112) {
        int j = i - 2048, qq = j >> 4, v1 = j & 15;
        float ang = (float)(qq * v1) * (1.0f / 32.0f);
        tabs[i] = f2{cospif(ang), sinpif(ang)};
    } else if (i < 3136) {
        int m = i - 2112;
        tabs[i] = f2{cospif((float)m * (1.0f / 1024.0f)),
                     sinpif((float)m * (1.0f / 1024.0f))};
    }
}

// ---------------- per-frame irfft: wave-per-frame four-step register FFT ----
// 1024 = 16 x 64 Bailey four-step (verified r10-r13). r11 structure exactly:
// 2 waves/128-thread block, 8KB LDS/wave, per-wave fence (no barrier).
// All twiddles from L1-resident tables; all complex math on packed f32.
__global__ __launch_bounds__(128) void fft_frames(
    const float* __restrict__ re, const float* __restrict__ im,
    const f2* __restrict__ tabs,
    unsigned short* __restrict__ Y)          // [BATCH][4][TOTALP] bf16
{
    __shared__ f2 tb[2][1024];               // 8KB per wave

    const int tid   = threadIdx.x;
    const int lane  = tid & 63;
    const int wv    = tid >> 6;
    const int frame = blockIdx.x * 2 + wv;
    const int b     = frame >> 11;
    const int t     = frame & (TFRAMES - 1);
    const float* rr = re + (size_t)frame * FBINS;
    const float* ii = im + (size_t)frame * FBINS;
    f2* tbw         = tb[wv];

    const f2* WT  = tabs;
    const f2* T2  = tabs + 1024;
    const f2* T64 = tabs + 2048;
    const f2* TP  = tabs + 2112;

    // ---- pack: zz[k1] = Z[64*k1 + lane] ----
    f2 zz[16];
    #pragma unroll
    for (int k1 = 0; k1 < 16; ++k1) {
        const int m = 64 * k1 + lane;
        f2 X  = f2{rr[m],        ii[m]};
        f2 M  = f2{rr[1024 - m], ii[1024 - m]};
        f2 Cc = M * f2{1.0f, -1.0f};              // conj(mirror)
        f2 E  = X + Cc;
        f2 O  = X - Cc;
        f2 z  = E + cjmul(cmul(TP[m], O));
        if (k1 == 0 && lane == 0)                  // m == 0: im parts drop
            z = f2{X.x + M.x, X.x - M.x};
        zz[k1] = z;
    }

    // ---- step 1: A = idft16 over k1 ----
    f2 A[16];
    idft16(A, zz);

    // ---- step 2: A[n1] *= W1024^{n1*lane} (table) ----
    #pragma unroll
    for (int n1 = 1; n1 < 16; ++n1)
        A[n1] = cmul(A[n1], T2[n1 * 64 + lane]);

    // ---- transpose write: row=lane, 8 x float4, chunk-rotated ----
    {
        float4* rowp = (float4*)&tbw[lane * 16];
        #pragma unroll
        for (int j = 0; j < 8; ++j) {
            f2 e = A[2 * j], o = A[2 * j + 1];
            rowp[(j + lane) & 7] = float4{e.x, e.y, o.x, o.y};
        }
    }
    // per-wave LDS dependence only: wait our own writes, fence the scheduler
    asm volatile("s_waitcnt lgkmcnt(0)" ::: "memory");
    __builtin_amdgcn_sched_barrier(0);

    // ---- regroup read: lane = (q = lane>>4, n1r = lane&15) ----
    const int q   = lane >> 4;
    const int n1r = lane & 15;
    f2 D[16];
    #pragma unroll
    for (int c1 = 0; c1 < 16; ++c1) {
        const int row = 4 * c1 + q;
        D[c1] = tbw[row * 16 + (((n1r >> 1) + row) & 7) * 2 + (n1r & 1)];
    }

    // ---- step 3a: E = idft16 over c1 ----
    f2 E[16];
    idft16(E, D);

    // ---- step 3b: E[v1] *= W64^{v1*q} (table) ----
    #pragma unroll
    for (int v1 = 1; v1 < 16; ++v1)
        E[v1] = cmul(E[v1], T64[q * 16 + v1]);

    // ---- step 3c: cross-lane idft4 over q + window + bf16 plane store ----
    unsigned short* Yb = Y + ((size_t)(b * 4 + (t & 3))) * TOTALP + t * HOPSZ;
    const int v2 = ((q & 1) << 1) | (q >> 1);          // bitrev2(q)
    const int nbase = n1r + (v2 << 8);
    #pragma unroll
    for (int v1 = 0; v1 < 16; ++v1) {
        f2 mine = E[v1];
        f2 oth  = f2{__shfl_xor(mine.x, 32), __shfl_xor(mine.y, 32)};
        f2 G    = (lane < 32) ? (mine + oth) : (oth - mine);
        f2 o2   = f2{__shfl_xor(G.x, 16), __shfl_xor(G.y, 16)};
        f2 res;
        if (q == 0)      res = G + o2;                 // -> v2=0
        else if (q == 1) res = o2 - G;                 // -> v2=2
        else if (q == 2) res = G + cjmul(o2);          // -> v2=1
        else             res = o2 - cjmul(G);          // -> v2=3
        const int n = nbase + (v1 << 4);
        f2 rw = res * WT[n];                           // window * (1/2048)
        unsigned pack;
        asm("v_cvt_pk_bf16_f32 %0, %1, %2" : "=v"(pack) : "v"(rw.x), "v"(rw.y));
        *(unsigned*)(Yb + 2 * n) = pack;
    }
}

// ---------------- final pass: gather 4 planes, divide by window-sumsquare ---
// Plane values are x*win (true windowed signal: the 1/2048 irfft norm is
// inside WT). Interior (4 full taps): sum win^2 = 1.5 exactly (Hann, hop=N/4)
// -> out = acc * 2/3. Edges use the generic loop.
__global__ __launch_bounds__(256) void final_pass(
    const unsigned short* __restrict__ Y,    // [BATCH][4][TOTALP]
    const f2*             __restrict__ tabs, // WT at offset 0
    float*                __restrict__ out)  // [BATCH][OUTLEN]
{
    const int tx = blockIdx.x * 256 + threadIdx.x;
    if (tx >= OUTLEN / 8) return;
    const int b  = blockIdx.y;
    const int n0 = tx * 8;
    const int p0 = n0 + 1024;

    float acc[8];
    #pragma unroll
    for (int j = 0; j < 8; ++j) acc[j] = 0.0f;

    if (p0 >= 1536 && p0 < 1048576) {
        // interior: exactly 4 taps, constant window-sumsquare = 1.5
        const int tmin = (p0 - 1536) >> 9;
        #pragma unroll
        for (int k = 0; k < 4; ++k) {
            const int t = tmin + k;
            const uint4 pv = *(const uint4*)(Y + ((size_t)(b * 4 + (t & 3))) * TOTALP + p0);
            const unsigned pw[4] = {pv.x, pv.y, pv.z, pv.w};
            #pragma unroll
            for (int j = 0; j < 4; ++j) {
                acc[2 * j]     += bf2f((unsigned short)(pw[j] & 0xffffu));
                acc[2 * j + 1] += bf2f((unsigned short)(pw[j] >> 16));
            }
        }
        const float inv = 2.0f / 3.0f;               // acc = sum(x*win); ws = 1.5
        float r[8];
        #pragma unroll
        for (int j = 0; j < 8; ++j) r[j] = acc[j] * inv;
        float4* o = (float4*)(out + (size_t)b * OUTLEN + n0);
        o[0] = float4{r[0], r[1], r[2], r[3]};
        o[1] = float4{r[4], r[5], r[6], r[7]};
        return;
    }

    int tmin = (p0 - 1536) >> 9;  if (tmin < 0) tmin = 0;
    int tmax = p0 >> 9;           if (tmax > TFRAMES - 1) tmax = TFRAMES - 1;
    float ws[8];
    #pragma unroll
    for (int j = 0; j < 8; ++j) ws[j] = 0.0f;
    for (int t = tmin; t <= tmax; ++t) {
        const int a0 = p0 - t * HOPSZ;        // 8-run fully inside [0,2048)
        const uint4 pv = *(const uint4*)(Y + ((size_t)(b * 4 + (t & 3))) * TOTALP + p0);
        const unsigned pw[4] = {pv.x, pv.y, pv.z, pv.w};
        #pragma unroll
        for (int j = 0; j < 4; ++j) {
            acc[2 * j]     += bf2f((unsigned short)(pw[j] & 0xffffu));
            acc[2 * j + 1] += bf2f((unsigned short)(pw[j] >> 16));
        }
        #pragma unroll
        for (int j = 0; j < 4; ++j) {
            f2 w = tabs[(a0 >> 1) + j];       // (win[a0+2j], win[a0+2j+1]) * s
            ws[2 * j]     += w.x * w.x;
            ws[2 * j + 1] += w.y * w.y;
        }
    }
    const float S2 = (1.0f / 2048.0f) * (1.0f / 2048.0f);
    float r[8];
    #pragma unroll
    for (int j = 0; j < 8; ++j) r[j] = acc[j] * S2 / fmaxf(ws[j], 2.4e-15f);
    float4* o = (float4*)(out + (size_t)b * OUTLEN + n0);
    o[0] = float4{r[0], r[1], r[2], r[3]};
    o[1] = float4{r[4], r[5], r[6], r[7]};
}

// ---------------- launch -----------------------------------------------------
extern "C" void kernel_launch(void* const* d_in, const int* in_sizes, int n_in,
                              void* d_out, int out_size, void* d_ws, size_t ws_size,
                              hipStream_t stream) {
    const float* re = (const float*)d_in[0];
    const float* im = (const float*)d_in[1];
    float* out = (float*)d_out;

    char* ws = (char*)d_ws;
    unsigned short* Y    = (unsigned short*)(ws);            // 8*4*1050112*2 = 67,207,168 B
    f2*             tabs = (f2*)           (ws + 67207168);  // 3136*8 = 25,088 B

    build_tabs<<<dim3(13),         256, 0, stream>>>(tabs);
    fft_frames<<<dim3(MROWS / 2),  128, 0, stream>>>(re, im, tabs, Y);
    final_pass<<<dim3(512, BATCH), 256, 0, stream>>>(Y, tabs, out);
}